// Round 3
// baseline (101.560 us; speedup 1.0000x reference)
//
#include <hip/hip_runtime.h>

// 1 sample per thread, scalar complex math, SGPR-resident gate constants.
// Round-2 post-mortem: (256,6) removed the round-1 spill (kernel fell out of
// the top-5, i.e. <44us). Remaining gap to the ~18us VALU-issue floor is
// latency at 6 waves/SIMD. The variational gate entries are wave-uniform ->
// hoist them to SGPRs via readfirstlane (v_fma reads 1 SGPR operand free).
// This drops the vector live set to ~50 regs -> (256,8) now fits WITHOUT the
// round-1 spill (that spill was st[]+constants all in VGPRs under a 64 cap).

struct C { float r, i; };

__device__ __forceinline__ float rfl(float v) {
    return __int_as_float(__builtin_amdgcn_readfirstlane(__float_as_int(v)));
}

__device__ __forceinline__ C cmul(C a, C b) {
    C o;
    o.r = fmaf(a.r, b.r, -(a.i * b.i));
    o.i = fmaf(a.r, b.i,   a.i * b.r);
    return o;
}

// o = u*a + w*b where u=(ur,ui), w=(wr,wi) are wave-uniform gate entries.
__device__ __forceinline__ C cmadd(float ur, float ui, float wr, float wi, C a, C b) {
    C o;
    o.r = fmaf(ur, a.r, fmaf(-ui, a.i, fmaf(wr, b.r, -(wi * b.i))));
    o.i = fmaf(ur, a.i, fmaf( ui, a.r, fmaf(wr, b.i,   wi * b.r)));
    return o;
}

// One 2x2 complex gate, entries as 8 uniform scalars (SGPR-resident).
struct G8 { float u00r, u00i, u01r, u01i, u10r, u10i, u11r, u11i; };

template <int BP>
__device__ __forceinline__ void apply_gate(C st[16], const G8& g) {
#pragma unroll
    for (int i = 0; i < 8; i++) {
        const int lo = ((i >> BP) << (BP + 1)) | (i & ((1 << BP) - 1));
        const int hi = lo | (1 << BP);
        const C a = st[lo], b = st[hi];
        st[lo] = cmadd(g.u00r, g.u00i, g.u01r, g.u01i, a, b);
        st[hi] = cmadd(g.u10r, g.u10i, g.u11r, g.u11i, a, b);
    }
}

// CNOT: pure register permutation (free at full unroll).
template <int CB, int TB>
__device__ __forceinline__ void cnot(C st[16]) {
#pragma unroll
    for (int i = 0; i < 16; i++) {
        if ((i & (1 << CB)) && !(i & (1 << TB))) {
            C t = st[i];
            st[i] = st[i | (1 << TB)];
            st[i | (1 << TB)] = t;
        }
    }
}

struct Enc { float r0, i0, r1, i1; };
// v_q = (cos(xn) e^{-i xn/2}, sin(xn) e^{+i xn/2}), xn = pi*tanh(x).
// HW v_sin/v_cos take REVOLUTIONS: sin(pi t/2) = v_sin(t/4), t in (-1,1) -> no range reduction.
__device__ __forceinline__ Enc encode(float xq) {
    const float ax = fabsf(xq);
    const float e  = __builtin_amdgcn_exp2f(ax * -2.8853900817779268f);  // exp(-2|x|)
    const float r  = __builtin_amdgcn_rcpf(1.0f + e);
    const float t  = copysignf((1.0f - e) * r, xq);                       // tanh(x)
    const float sh = __builtin_amdgcn_sinf(t * 0.25f);                    // sin(pi t/2)
    const float ch = __builtin_amdgcn_cosf(t * 0.25f);                    // cos(pi t/2)
    const float s  = 2.0f * sh * ch;                                      // sin(pi t)
    const float c  = fmaf(-2.0f * sh, sh, 1.0f);                          // cos(pi t)
    return {c * ch, -(c * sh), s * ch, s * sh};
}

__global__ __launch_bounds__(256, 8) void qlayer_kernel(const float* __restrict__ x,
                                                        const float* __restrict__ qw,
                                                        float* __restrict__ out, int B) {
    __shared__ float4 Ug[12][2];
    const int tid = threadIdx.x;
    if (tid < 12) {
        const float phi = qw[tid * 3 + 0];
        const float th  = qw[tid * 3 + 1];
        const float om  = qw[tid * 3 + 2];
        // Rot = RZ(om) RY(th) RZ(phi)
        float s, c;   __sincosf(0.5f * th, &s, &c);
        float sa, ca; __sincosf(0.5f * (phi + om), &sa, &ca);
        float sb, cb; __sincosf(0.5f * (phi - om), &sb, &cb);
        Ug[tid][0] = make_float4(c * ca, -c * sa, -s * cb, -s * sb);
        Ug[tid][1] = make_float4(s * cb, -s * sb, c * ca, c * sa);
    }
    __syncthreads();

    // Hoist the 8 variational gates (layers 1-2) to SGPRs: wave-uniform values,
    // readfirstlane pins them in the scalar file (64 + ~20 internal <= 102).
    G8 g[8];
#pragma unroll
    for (int k = 0; k < 8; k++) {
        const float4 A = Ug[4 + k][0], Bv = Ug[4 + k][1];
        g[k].u00r = rfl(A.x);  g[k].u00i = rfl(A.y);
        g[k].u01r = rfl(A.z);  g[k].u01i = rfl(A.w);
        g[k].u10r = rfl(Bv.x); g[k].u10i = rfl(Bv.y);
        g[k].u11r = rfl(Bv.z); g[k].u11i = rfl(Bv.w);
    }

    const int b = blockIdx.x * 256 + tid;
    if (b >= B) return;

    const float4 xv = reinterpret_cast<const float4*>(x)[b];
    const float xs[4] = {xv.x, xv.y, xv.z, xv.w};

    // Encode + merge layer-0 Rot into the per-qubit 2-vectors (still product state).
    C v[4][2];
#pragma unroll
    for (int q = 0; q < 4; q++) {
        const Enc e = encode(xs[q]);
        const C a{e.r0, e.i0}, bv{e.r1, e.i1};
        const float4 A4 = Ug[q][0], B4 = Ug[q][1];
        v[q][0] = cmadd(A4.x, A4.y, A4.z, A4.w, a, bv);
        v[q][1] = cmadd(B4.x, B4.y, B4.z, B4.w, a, bv);
    }

    // Outer product: st[(i01<<2)|i23] = t01[i01] * t23[i23]
    C t01[4], t23[4];
#pragma unroll
    for (int i = 0; i < 4; i++) {
        t01[i] = cmul(v[0][(i >> 1) & 1], v[1][i & 1]);
        t23[i] = cmul(v[2][(i >> 1) & 1], v[3][i & 1]);
    }
    C st[16];
#pragma unroll
    for (int i = 0; i < 16; i++) st[i] = cmul(t01[i >> 2], t23[i & 3]);

    // Layer-0 CNOT ring (qubit q -> bit 3-q).
    cnot<3, 2>(st); cnot<2, 1>(st); cnot<1, 0>(st); cnot<0, 3>(st);

    // Layer 1 (SGPR gates)
    apply_gate<3>(st, g[0]);
    apply_gate<2>(st, g[1]);
    apply_gate<1>(st, g[2]);
    apply_gate<0>(st, g[3]);
    cnot<3, 2>(st); cnot<2, 1>(st); cnot<1, 0>(st); cnot<0, 3>(st);
    // Layer 2 (SGPR gates)
    apply_gate<3>(st, g[4]);
    apply_gate<2>(st, g[5]);
    apply_gate<1>(st, g[6]);
    apply_gate<0>(st, g[7]);
    cnot<3, 2>(st); cnot<2, 1>(st); cnot<1, 0>(st); cnot<0, 3>(st);

    // Readout: normalized state => <Z_q> = 1 - 2*sum_{bit(3-q)=1} |amp|^2.
    float s0 = 0.f, s1 = 0.f, s2 = 0.f, s3 = 0.f;
#pragma unroll
    for (int i = 0; i < 16; i++) {
        const float p = fmaf(st[i].r, st[i].r, st[i].i * st[i].i);
        if (i & 8) s3 += p;
        if (i & 4) s2 += p;
        if (i & 2) s1 += p;
        if (i & 1) s0 += p;
    }

    float4 ev;
    ev.x = fmaf(-2.0f, s3, 1.0f);
    ev.y = fmaf(-2.0f, s2, 1.0f);
    ev.z = fmaf(-2.0f, s1, 1.0f);
    ev.w = fmaf(-2.0f, s0, 1.0f);
    reinterpret_cast<float4*>(out)[b] = ev;
}

extern "C" void kernel_launch(void* const* d_in, const int* in_sizes, int n_in,
                              void* d_out, int out_size, void* d_ws, size_t ws_size,
                              hipStream_t stream) {
    const float* x  = (const float*)d_in[0];
    const float* qw = (const float*)d_in[1];
    float* out = (float*)d_out;
    const int B = in_sizes[0] / 4;
    const int blocks = (B + 255) / 256;   // 1 sample per thread
    qlayer_kernel<<<blocks, 256, 0, stream>>>(x, qw, out, B);
}

// Round 5
// 84.396 us; speedup vs baseline: 1.2034x; 1.2034x over previous
//
#include <hip/hip_runtime.h>

// MFMA-tail rewrite, take 2.
// The tail (ring0, L1, ring, L2, ring) is one fixed 32x32 real matrix W shared
// by all samples -> C[B,32] = A[B,32]*W^T on the matrix pipe via
// v_mfma_f32_16x16x32_f16, split-f16 (hi + lo*2048, 3 mfmas, f32 accum).
// Round-4 post-mortem: "barrier-free lockstep" was wrong. The pack->A-read and
// C-store->readback handoffs are CROSS-LANE through LDS; per-lane alias
// analysis proves this lane's addresses disjoint and the scheduler hoists the
// LDS reads above the stores -> stale reads, nondeterministic garbage
// (absmax 1.5 / 468 across runs). Fix: __syncthreads() at both handoffs
// (full compiler fence + lgkmcnt drain); ~200 cycles total, noise at 20us.

using f16x8 = __attribute__((ext_vector_type(8))) _Float16;
using f32x4 = __attribute__((ext_vector_type(4))) float;

struct C { float r, i; };

__device__ __forceinline__ C cmul(C a, C b) {
    C o;
    o.r = fmaf(a.r, b.r, -(a.i * b.i));
    o.i = fmaf(a.r, b.i,   a.i * b.r);
    return o;
}

// o = u*a + w*b where u=(ur,ui), w=(wr,wi) are gate entries.
__device__ __forceinline__ C cmadd(float ur, float ui, float wr, float wi, C a, C b) {
    C o;
    o.r = fmaf(ur, a.r, fmaf(-ui, a.i, fmaf(wr, b.r, -(wi * b.i))));
    o.i = fmaf(ur, a.i, fmaf( ui, a.r, fmaf(wr, b.i,   wi * b.r)));
    return o;
}

// Apply 2x2 complex gate (A4=[u00.re u00.im u01.re u01.im], B4=[u10 u11]) to bit BP.
template <int BP>
__device__ __forceinline__ void apply_gate(C st[16], float4 A4, float4 B4) {
#pragma unroll
    for (int i = 0; i < 8; i++) {
        const int lo = ((i >> BP) << (BP + 1)) | (i & ((1 << BP) - 1));
        const int hi = lo | (1 << BP);
        const C a = st[lo], b = st[hi];
        st[lo] = cmadd(A4.x, A4.y, A4.z, A4.w, a, b);
        st[hi] = cmadd(B4.x, B4.y, B4.z, B4.w, a, b);
    }
}

// CNOT: pure register permutation (free at full unroll).
template <int CB, int TB>
__device__ __forceinline__ void cnot(C st[16]) {
#pragma unroll
    for (int i = 0; i < 16; i++) {
        if ((i & (1 << CB)) && !(i & (1 << TB))) {
            C t = st[i];
            st[i] = st[i | (1 << TB)];
            st[i | (1 << TB)] = t;
        }
    }
}

struct Enc { float r0, i0, r1, i1; };
// v_q = (cos(xn) e^{-i xn/2}, sin(xn) e^{+i xn/2}), xn = pi*tanh(x).
// HW v_sin/v_cos take REVOLUTIONS: sin(pi t/2) = v_sin(t/4), t in (-1,1) -> no range reduction.
__device__ __forceinline__ Enc encode(float xq) {
    const float ax = fabsf(xq);
    const float e  = __builtin_amdgcn_exp2f(ax * -2.8853900817779268f);  // exp(-2|x|)
    const float r  = __builtin_amdgcn_rcpf(1.0f + e);
    const float t  = copysignf((1.0f - e) * r, xq);                       // tanh(x)
    const float sh = __builtin_amdgcn_sinf(t * 0.25f);                    // sin(pi t/2)
    const float ch = __builtin_amdgcn_cosf(t * 0.25f);                    // cos(pi t/2)
    const float s  = 2.0f * sh * ch;                                      // sin(pi t)
    const float c  = fmaf(-2.0f * sh, sh, 1.0f);                          // cos(pi t)
    return {c * ch, -(c * sh), s * ch, s * sh};
}

// Workspace layout (bytes): [0,2048) Whi f16[32][32]; [2048,4096) Wlo (x2048);
// [4096,4224) layer-0 gates: float4[4][2].
#define WS_WLO 2048
#define WS_UG0 4096

// ---------------- Kernel 1: compose tail matrix W (1 block, 64 threads) ------
__global__ void qcompose_kernel(const float* __restrict__ qw, float* __restrict__ ws) {
    __shared__ float4 Ug[12][2];
    const int tid = threadIdx.x;
    if (tid < 12) {
        const float phi = qw[tid * 3 + 0];
        const float th  = qw[tid * 3 + 1];
        const float om  = qw[tid * 3 + 2];
        // Rot = RZ(om) RY(th) RZ(phi)
        float s, c;   __sincosf(0.5f * th, &s, &c);
        float sa, ca; __sincosf(0.5f * (phi + om), &sa, &ca);
        float sb, cb; __sincosf(0.5f * (phi - om), &sb, &cb);
        Ug[tid][0] = make_float4(c * ca, -c * sa, -s * cb, -s * sb);
        Ug[tid][1] = make_float4(s * cb, -s * sb, c * ca, c * sa);
    }
    __syncthreads();

    if (tid < 4) {  // export layer-0 gates for the main kernel
        float4* o = reinterpret_cast<float4*>(reinterpret_cast<char*>(ws) + WS_UG0);
        o[2 * tid]     = Ug[tid][0];
        o[2 * tid + 1] = Ug[tid][1];
    }

    if (tid < 16) {
        // Push basis state e_tid through the tail: ring0, L1, ring, L2, ring.
        C st[16];
#pragma unroll
        for (int i = 0; i < 16; i++) { st[i].r = 0.0f; st[i].i = 0.0f; }
        st[tid].r = 1.0f;

        cnot<3, 2>(st); cnot<2, 1>(st); cnot<1, 0>(st); cnot<0, 3>(st);
        apply_gate<3>(st, Ug[4][0], Ug[4][1]);
        apply_gate<2>(st, Ug[5][0], Ug[5][1]);
        apply_gate<1>(st, Ug[6][0], Ug[6][1]);
        apply_gate<0>(st, Ug[7][0], Ug[7][1]);
        cnot<3, 2>(st); cnot<2, 1>(st); cnot<1, 0>(st); cnot<0, 3>(st);
        apply_gate<3>(st, Ug[8][0], Ug[8][1]);
        apply_gate<2>(st, Ug[9][0], Ug[9][1]);
        apply_gate<1>(st, Ug[10][0], Ug[10][1]);
        apply_gate<0>(st, Ug[11][0], Ug[11][1]);
        cnot<3, 2>(st); cnot<2, 1>(st); cnot<1, 0>(st); cnot<0, 3>(st);

        // Real representation: out[j] = sum_k W[j][k] in[k], k/j = 2*dim + (0:re,1:im).
        // Column pair k0=2*tid (re-in), k1=2*tid+1 (im-in):
        //   W[2d][2t]=Tr  W[2d+1][2t]=Ti  W[2d][2t+1]=-Ti  W[2d+1][2t+1]=Tr
        _Float16* whi = reinterpret_cast<_Float16*>(ws);
        _Float16* wlo = reinterpret_cast<_Float16*>(reinterpret_cast<char*>(ws) + WS_WLO);
        const int k0 = 2 * tid, k1 = k0 + 1;
#pragma unroll
        for (int d = 0; d < 16; d++) {
            const int j0 = 2 * d, j1 = j0 + 1;
            const float vr = st[d].r, vi = st[d].i;
            float v[4]  = {vr, vi, -vi, vr};
            int   jj[4] = {j0, j1, j0, j1};
            int   kk[4] = {k0, k0, k1, k1};
#pragma unroll
            for (int e = 0; e < 4; e++) {
                _Float16 h = (_Float16)v[e];
                _Float16 l = (_Float16)((v[e] - (float)h) * 2048.0f);  // lo pre-scaled: dodge f16 denorms
                whi[jj[e] * 32 + kk[e]] = h;
                wlo[jj[e] * 32 + kk[e]] = l;
            }
        }
    }
}

// ---------------- Kernel 2: main, MFMA tail, 2 barriers -----------------------
// LDS slab per wave: 64 samples x 144 B (hi f16[32] @0, lo f16[32] @64, pad 16).
// 144 B = 36 words -> 2-way bank aliasing only (free, m136).
// C (f32[32], 128 B) overwrites the consumed A rows in place (safe: stores are
// data-dependent on the reads within an iteration; disjoint rows across).
__global__ __launch_bounds__(256, 4) void qlayer_kernel(const float* __restrict__ x,
                                                        const float* __restrict__ ws,
                                                        float* __restrict__ out, int B) {
    __shared__ __align__(16) unsigned char lds[4 * 64 * 144];
    const int tid  = threadIdx.x;
    const int lane = tid & 63;
    const int wid  = tid >> 6;
    char* slab  = reinterpret_cast<char*>(lds) + wid * (64 * 144);
    char* myrow = slab + lane * 144;

    const char* wsb = reinterpret_cast<const char*>(ws);

    // B fragments (wave-uniform matrix, lane-mapped): row j=(lane&15)+16n over
    // k-chunk 8*(lane>>4) .. +8 (same contiguous-k order as the A fragments;
    // any HW k-permutation is identical on A and B and cancels in the dot).
    const int jrow = lane & 15;
    const int kb   = (lane >> 4) * 16;  // byte offset of k-chunk in a 64 B row
    const f16x8 Bh0 = *reinterpret_cast<const f16x8*>(wsb + jrow * 64 + kb);
    const f16x8 Bh1 = *reinterpret_cast<const f16x8*>(wsb + (jrow + 16) * 64 + kb);
    const f16x8 Bl0 = *reinterpret_cast<const f16x8*>(wsb + WS_WLO + jrow * 64 + kb);
    const f16x8 Bl1 = *reinterpret_cast<const f16x8*>(wsb + WS_WLO + (jrow + 16) * 64 + kb);
    const float4* ug0 = reinterpret_cast<const float4*>(wsb + WS_UG0);

    const int b  = blockIdx.x * 256 + tid;
    const int bl = (b < B) ? b : (B - 1);   // clamp: OOB lanes still join barriers/MFMA
    const float4 xv = reinterpret_cast<const float4*>(x)[bl];
    const float xs[4] = {xv.x, xv.y, xv.z, xv.w};

    // Front end: encode + merge layer-0 Rot (still product state).
    C v[4][2];
#pragma unroll
    for (int q = 0; q < 4; q++) {
        const Enc e = encode(xs[q]);
        const C a{e.r0, e.i0}, bv{e.r1, e.i1};
        const float4 A4 = ug0[2 * q], B4 = ug0[2 * q + 1];
        v[q][0] = cmadd(A4.x, A4.y, A4.z, A4.w, a, bv);
        v[q][1] = cmadd(B4.x, B4.y, B4.z, B4.w, a, bv);
    }

    // Outer product: st[(i01<<2)|i23] = t01[i01] * t23[i23]. (ring0 lives in W.)
    C t01[4], t23[4];
#pragma unroll
    for (int i = 0; i < 4; i++) {
        t01[i] = cmul(v[0][(i >> 1) & 1], v[1][i & 1]);
        t23[i] = cmul(v[2][(i >> 1) & 1], v[3][i & 1]);
    }
    C st[16];
#pragma unroll
    for (int i = 0; i < 16; i++) st[i] = cmul(t01[i >> 2], t23[i & 3]);

    // Split-f16 pack, store to my LDS row (k-order: re,im interleaved).
#pragma unroll
    for (int c = 0; c < 4; c++) {
        f16x8 vh, vl;
#pragma unroll
        for (int d = 0; d < 4; d++) {
            const float fr = st[4 * c + d].r, fi = st[4 * c + d].i;
            const _Float16 hr = (_Float16)fr, hi_ = (_Float16)fi;
            vh[2 * d]     = hr;
            vh[2 * d + 1] = hi_;
            vl[2 * d]     = (_Float16)((fr - (float)hr) * 2048.0f);
            vl[2 * d + 1] = (_Float16)((fi - (float)hi_) * 2048.0f);
        }
        *reinterpret_cast<f16x8*>(myrow + c * 16)      = vh;
        *reinterpret_cast<f16x8*>(myrow + 64 + c * 16) = vl;
    }

    // CROSS-LANE handoff #1: lanes read rows written by other lanes.
    __syncthreads();

    // Tail as GEMM: C[s,j] = sum_k A[s,k] W[j][k]; 4 M-tiles x 2 N-tiles,
    // 3 mfmas each (split-f16). A-frag: sample 16m+(lane&15), k-chunk 8*(lane>>4).
    const f32x4 Z = {0.f, 0.f, 0.f, 0.f};
#pragma unroll
    for (int m = 0; m < 4; m++) {
        const char* arow = slab + (16 * m + (lane & 15)) * 144 + kb;
        const f16x8 Ah = *reinterpret_cast<const f16x8*>(arow);
        const f16x8 Al = *reinterpret_cast<const f16x8*>(arow + 64);

        f32x4 main0 = __builtin_amdgcn_mfma_f32_16x16x32_f16(Ah, Bh0, Z, 0, 0, 0);
        f32x4 corr0 = __builtin_amdgcn_mfma_f32_16x16x32_f16(Ah, Bl0, Z, 0, 0, 0);
        corr0       = __builtin_amdgcn_mfma_f32_16x16x32_f16(Al, Bh0, corr0, 0, 0, 0);
        f32x4 main1 = __builtin_amdgcn_mfma_f32_16x16x32_f16(Ah, Bh1, Z, 0, 0, 0);
        f32x4 corr1 = __builtin_amdgcn_mfma_f32_16x16x32_f16(Ah, Bl1, Z, 0, 0, 0);
        corr1       = __builtin_amdgcn_mfma_f32_16x16x32_f16(Al, Bh1, corr1, 0, 0, 0);

        // C/D layout (m89-verified): col(N)=lane&15, row(M)=4*(lane>>4)+r.
        const int srow = 16 * m + 4 * (lane >> 4);
        const int col  = lane & 15;
#pragma unroll
        for (int r = 0; r < 4; r++) {
            float* crow = reinterpret_cast<float*>(slab + (srow + r) * 144);
            crow[col]      = fmaf(corr0[r], 4.8828125e-4f, main0[r]);  // + lo/2048
            crow[16 + col] = fmaf(corr1[r], 4.8828125e-4f, main1[r]);
        }
    }

    // CROSS-LANE handoff #2: my row's 32 floats were written by other lanes.
    __syncthreads();

    float cv[32];
#pragma unroll
    for (int c = 0; c < 8; c++) {
        const float4 q4 = *reinterpret_cast<const float4*>(myrow + c * 16);
        cv[4 * c] = q4.x; cv[4 * c + 1] = q4.y; cv[4 * c + 2] = q4.z; cv[4 * c + 3] = q4.w;
    }

    // Readout: <Z_q> = 1 - 2*sum_{bit(3-q)=1} |amp|^2.
    float s0 = 0.f, s1 = 0.f, s2 = 0.f, s3 = 0.f;
#pragma unroll
    for (int d = 0; d < 16; d++) {
        const float p = fmaf(cv[2 * d], cv[2 * d], cv[2 * d + 1] * cv[2 * d + 1]);
        if (d & 8) s3 += p;
        if (d & 4) s2 += p;
        if (d & 2) s1 += p;
        if (d & 1) s0 += p;
    }

    if (b < B) {
        float4 ev;
        ev.x = fmaf(-2.0f, s3, 1.0f);
        ev.y = fmaf(-2.0f, s2, 1.0f);
        ev.z = fmaf(-2.0f, s1, 1.0f);
        ev.w = fmaf(-2.0f, s0, 1.0f);
        reinterpret_cast<float4*>(out)[b] = ev;
    }
}

extern "C" void kernel_launch(void* const* d_in, const int* in_sizes, int n_in,
                              void* d_out, int out_size, void* d_ws, size_t ws_size,
                              hipStream_t stream) {
    const float* x  = (const float*)d_in[0];
    const float* qw = (const float*)d_in[1];
    float* out = (float*)d_out;
    float* ws  = (float*)d_ws;
    const int B = in_sizes[0] / 4;
    const int blocks = (B + 255) / 256;
    qcompose_kernel<<<1, 64, 0, stream>>>(qw, ws);
    qlayer_kernel<<<blocks, 256, 0, stream>>>(x, ws, out, B);
}

// Round 6
// 82.887 us; speedup vs baseline: 1.2253x; 1.0182x over previous
//
#include <hip/hip_runtime.h>

// MFMA-tail, take 3: transposed GEMM + in-register readout.
// Tail = fixed 32x32 real matrix W (split-f16: Whi + Wlo/2048, exact to f32).
// This round: D = W * S^T (operands swapped) so D col=sample, row=j -> each
// lane holds 8 consecutive j's of ONE sample; probs + signed marginals happen
// in f32 registers + 2-stage shfl_xor(16,32) reduce. Removes the C->LDS->
// readback round trip, its fence, and f16-C rounding. Samples pack hi-only
// f16 (err ~2^-12, EV tail ~1e-3 << 0.0158 headroom); pack fused into the
// outer product (st dies immediately -> peak VGPR ~60). LDS rows 80 B ->
// 20 KiB/WG; block __syncthreads replaced by a WAVE-level fence (slabs are
// per-wave; asm memory clobber + lgkmcnt(0) orders the DS ops, the round-4
// hazard was compiler reordering). launch_bounds(256,6) -> 6 waves/SIMD.

using f16x8 = __attribute__((ext_vector_type(8))) _Float16;
using f32x4 = __attribute__((ext_vector_type(4))) float;

struct C { float r, i; };

__device__ __forceinline__ C cmul(C a, C b) {
    C o;
    o.r = fmaf(a.r, b.r, -(a.i * b.i));
    o.i = fmaf(a.r, b.i,   a.i * b.r);
    return o;
}

// o = u*a + w*b where u=(ur,ui), w=(wr,wi) are gate entries.
__device__ __forceinline__ C cmadd(float ur, float ui, float wr, float wi, C a, C b) {
    C o;
    o.r = fmaf(ur, a.r, fmaf(-ui, a.i, fmaf(wr, b.r, -(wi * b.i))));
    o.i = fmaf(ur, a.i, fmaf( ui, a.r, fmaf(wr, b.i,   wi * b.r)));
    return o;
}

// Apply 2x2 complex gate (A4=[u00.re u00.im u01.re u01.im], B4=[u10 u11]) to bit BP.
template <int BP>
__device__ __forceinline__ void apply_gate(C st[16], float4 A4, float4 B4) {
#pragma unroll
    for (int i = 0; i < 8; i++) {
        const int lo = ((i >> BP) << (BP + 1)) | (i & ((1 << BP) - 1));
        const int hi = lo | (1 << BP);
        const C a = st[lo], b = st[hi];
        st[lo] = cmadd(A4.x, A4.y, A4.z, A4.w, a, b);
        st[hi] = cmadd(B4.x, B4.y, B4.z, B4.w, a, b);
    }
}

// CNOT: pure register permutation (free at full unroll).
template <int CB, int TB>
__device__ __forceinline__ void cnot(C st[16]) {
#pragma unroll
    for (int i = 0; i < 16; i++) {
        if ((i & (1 << CB)) && !(i & (1 << TB))) {
            C t = st[i];
            st[i] = st[i | (1 << TB)];
            st[i | (1 << TB)] = t;
        }
    }
}

struct Enc { float r0, i0, r1, i1; };
// v_q = (cos(xn) e^{-i xn/2}, sin(xn) e^{+i xn/2}), xn = pi*tanh(x).
// HW v_sin/v_cos take REVOLUTIONS: sin(pi t/2) = v_sin(t/4), t in (-1,1) -> no range reduction.
__device__ __forceinline__ Enc encode(float xq) {
    const float ax = fabsf(xq);
    const float e  = __builtin_amdgcn_exp2f(ax * -2.8853900817779268f);  // exp(-2|x|)
    const float r  = __builtin_amdgcn_rcpf(1.0f + e);
    const float t  = copysignf((1.0f - e) * r, xq);                       // tanh(x)
    const float sh = __builtin_amdgcn_sinf(t * 0.25f);                    // sin(pi t/2)
    const float ch = __builtin_amdgcn_cosf(t * 0.25f);                    // cos(pi t/2)
    const float s  = 2.0f * sh * ch;                                      // sin(pi t)
    const float c  = fmaf(-2.0f * sh, sh, 1.0f);                          // cos(pi t)
    return {c * ch, -(c * sh), s * ch, s * sh};
}

// Wave-level LDS fence: orders this wave's DS writes before subsequent DS reads.
// Slabs are per-wave and lanes are lockstep, so no block barrier is needed; the
// asm memory clobber stops compiler reordering (the round-4 bug), lgkmcnt(0)
// drains the DS queue, sched_barrier pins the point (rule #18 defense).
__device__ __forceinline__ void wave_lds_fence() {
    asm volatile("s_waitcnt lgkmcnt(0)" ::: "memory");
    __builtin_amdgcn_sched_barrier(0);
}

// Workspace layout (bytes): [0,2048) Whi f16[32][32]; [2048,4096) Wlo (x2048);
// [4096,4224) layer-0 gates: float4[4][2].
#define WS_WLO 2048
#define WS_UG0 4096
#define ROWB 80   // LDS row stride: 64 B data + 16 pad (2-way banks per 16-lane phase)

// ---------------- Kernel 1: compose tail matrix W (1 block, 64 threads) ------
__global__ void qcompose_kernel(const float* __restrict__ qw, float* __restrict__ ws) {
    __shared__ float4 Ug[12][2];
    const int tid = threadIdx.x;
    if (tid < 12) {
        const float phi = qw[tid * 3 + 0];
        const float th  = qw[tid * 3 + 1];
        const float om  = qw[tid * 3 + 2];
        // Rot = RZ(om) RY(th) RZ(phi)
        float s, c;   __sincosf(0.5f * th, &s, &c);
        float sa, ca; __sincosf(0.5f * (phi + om), &sa, &ca);
        float sb, cb; __sincosf(0.5f * (phi - om), &sb, &cb);
        Ug[tid][0] = make_float4(c * ca, -c * sa, -s * cb, -s * sb);
        Ug[tid][1] = make_float4(s * cb, -s * sb, c * ca, c * sa);
    }
    __syncthreads();

    if (tid < 4) {  // export layer-0 gates for the main kernel
        float4* o = reinterpret_cast<float4*>(reinterpret_cast<char*>(ws) + WS_UG0);
        o[2 * tid]     = Ug[tid][0];
        o[2 * tid + 1] = Ug[tid][1];
    }

    if (tid < 16) {
        // Push basis state e_tid through the tail: ring0, L1, ring, L2, ring.
        C st[16];
#pragma unroll
        for (int i = 0; i < 16; i++) { st[i].r = 0.0f; st[i].i = 0.0f; }
        st[tid].r = 1.0f;

        cnot<3, 2>(st); cnot<2, 1>(st); cnot<1, 0>(st); cnot<0, 3>(st);
        apply_gate<3>(st, Ug[4][0], Ug[4][1]);
        apply_gate<2>(st, Ug[5][0], Ug[5][1]);
        apply_gate<1>(st, Ug[6][0], Ug[6][1]);
        apply_gate<0>(st, Ug[7][0], Ug[7][1]);
        cnot<3, 2>(st); cnot<2, 1>(st); cnot<1, 0>(st); cnot<0, 3>(st);
        apply_gate<3>(st, Ug[8][0], Ug[8][1]);
        apply_gate<2>(st, Ug[9][0], Ug[9][1]);
        apply_gate<1>(st, Ug[10][0], Ug[10][1]);
        apply_gate<0>(st, Ug[11][0], Ug[11][1]);
        cnot<3, 2>(st); cnot<2, 1>(st); cnot<1, 0>(st); cnot<0, 3>(st);

        // Real representation: out[j] = sum_k W[j][k] in[k], k/j = 2*dim + (0:re,1:im).
        // Column pair k0=2*tid (re-in), k1=2*tid+1 (im-in):
        //   W[2d][2t]=Tr  W[2d+1][2t]=Ti  W[2d][2t+1]=-Ti  W[2d+1][2t+1]=Tr
        _Float16* whi = reinterpret_cast<_Float16*>(ws);
        _Float16* wlo = reinterpret_cast<_Float16*>(reinterpret_cast<char*>(ws) + WS_WLO);
        const int k0 = 2 * tid, k1 = k0 + 1;
#pragma unroll
        for (int d = 0; d < 16; d++) {
            const int j0 = 2 * d, j1 = j0 + 1;
            const float vr = st[d].r, vi = st[d].i;
            float v[4]  = {vr, vi, -vi, vr};
            int   jj[4] = {j0, j1, j0, j1};
            int   kk[4] = {k0, k0, k1, k1};
#pragma unroll
            for (int e = 0; e < 4; e++) {
                _Float16 h = (_Float16)v[e];
                _Float16 l = (_Float16)((v[e] - (float)h) * 2048.0f);  // lo pre-scaled: dodge f16 denorms
                whi[jj[e] * 32 + kk[e]] = h;
                wlo[jj[e] * 32 + kk[e]] = l;
            }
        }
    }
}

// ---------------- Kernel 2: main, transposed MFMA tail, wave-local -----------
__global__ __launch_bounds__(256, 6) void qlayer_kernel(const float* __restrict__ x,
                                                        const float* __restrict__ ws,
                                                        float* __restrict__ out, int B) {
    __shared__ __align__(16) unsigned char lds[4 * 64 * ROWB];   // 20 KiB/WG
    const int tid  = threadIdx.x;
    const int lane = tid & 63;
    const int wid  = tid >> 6;
    char* slab  = reinterpret_cast<char*>(lds) + wid * (64 * ROWB);
    char* myrow = slab + lane * ROWB;

    const char* wsb = reinterpret_cast<const char*>(ws);

    // W fragments = MFMA *A*-operand (M=j). Lane holds W row (lane&15) [+16 for
    // the 2nd M-tile], k-chunk 8*(lane>>4) — identical addressing to the
    // round-5-verified fragment code, operands swapped in the mfma call.
    const int jrow = lane & 15;
    const int kb   = (lane >> 4) * 16;  // byte offset of k-chunk in a 64 B row
    const f16x8 Wh0 = *reinterpret_cast<const f16x8*>(wsb + jrow * 64 + kb);
    const f16x8 Wh1 = *reinterpret_cast<const f16x8*>(wsb + (jrow + 16) * 64 + kb);
    const f16x8 Wl0 = *reinterpret_cast<const f16x8*>(wsb + WS_WLO + jrow * 64 + kb);
    const f16x8 Wl1 = *reinterpret_cast<const f16x8*>(wsb + WS_WLO + (jrow + 16) * 64 + kb);
    const float4* ug0 = reinterpret_cast<const float4*>(wsb + WS_UG0);

    const int b  = blockIdx.x * 256 + tid;
    const int bl = (b < B) ? b : (B - 1);   // clamp: OOB lanes still join MFMA/shuffles
    const float4 xv = reinterpret_cast<const float4*>(x)[bl];
    const float xs[4] = {xv.x, xv.y, xv.z, xv.w};

    // Front end: encode + merge layer-0 Rot (still product state).
    C v[4][2];
#pragma unroll
    for (int q = 0; q < 4; q++) {
        const Enc e = encode(xs[q]);
        const C a{e.r0, e.i0}, bv{e.r1, e.i1};
        const float4 A4 = ug0[2 * q], B4 = ug0[2 * q + 1];
        v[q][0] = cmadd(A4.x, A4.y, A4.z, A4.w, a, bv);
        v[q][1] = cmadd(B4.x, B4.y, B4.z, B4.w, a, bv);
    }

    // Outer product fused with f16 pack: st[i] dies immediately -> low VGPR peak.
    C t01[4], t23[4];
#pragma unroll
    for (int i = 0; i < 4; i++) {
        t01[i] = cmul(v[0][(i >> 1) & 1], v[1][i & 1]);
        t23[i] = cmul(v[2][(i >> 1) & 1], v[3][i & 1]);
    }
    f16x8 vh[4];
#pragma unroll
    for (int i = 0; i < 16; i++) {
        const C s = cmul(t01[i >> 2], t23[i & 3]);
        vh[i >> 2][2 * (i & 3)]     = (_Float16)s.r;
        vh[i >> 2][2 * (i & 3) + 1] = (_Float16)s.i;
    }
#pragma unroll
    for (int c = 0; c < 4; c++)
        *reinterpret_cast<f16x8*>(myrow + c * 16) = vh[c];

    // CROSS-LANE handoff (within this wave only): fence, no block barrier.
    wave_lds_fence();

    const int g = lane >> 4;
    const float f1 = (g & 1) ? 1.0f : 0.0f;   // d&2 mask (per-lane constant)
    const float f2 = (g & 2) ? 1.0f : 0.0f;   // d&4 mask
    const f32x4 Z = {0.f, 0.f, 0.f, 0.f};
    float e0 = 0.f, e1 = 0.f, e2 = 0.f, e3 = 0.f;

    // Tail: D = W * S^T. D col = sample = lane&15, row = j = 16*Mtile + 4g + r.
    // Lane holds j = 4g..4g+3 (c0) and 16+4g..+3 (c1) of sample 16n+(lane&15):
    // complex dims d = 2g, 2g+1 (c0) and 8+2g, 8+2g+1 (c1).
#pragma unroll
    for (int n = 0; n < 4; n++) {
        const f16x8 S = *reinterpret_cast<const f16x8*>(slab + (16 * n + jrow) * ROWB + kb);
        f32x4 m0 = __builtin_amdgcn_mfma_f32_16x16x32_f16(Wh0, S, Z, 0, 0, 0);
        f32x4 l0 = __builtin_amdgcn_mfma_f32_16x16x32_f16(Wl0, S, Z, 0, 0, 0);
        f32x4 m1 = __builtin_amdgcn_mfma_f32_16x16x32_f16(Wh1, S, Z, 0, 0, 0);
        f32x4 l1 = __builtin_amdgcn_mfma_f32_16x16x32_f16(Wl1, S, Z, 0, 0, 0);

        float c0[4], c1[4];
#pragma unroll
        for (int r = 0; r < 4; r++) {
            c0[r] = fmaf(l0[r], 4.8828125e-4f, m0[r]);   // + lo/2048
            c1[r] = fmaf(l1[r], 4.8828125e-4f, m1[r]);
        }
        // probs of the 4 dims this lane owns (all f32, exact squares)
        const float p0 = fmaf(c0[1], c0[1], c0[0] * c0[0]);   // d = 2g
        const float p1 = fmaf(c0[3], c0[3], c0[2] * c0[2]);   // d = 2g+1
        const float p2 = fmaf(c1[1], c1[1], c1[0] * c1[0]);   // d = 8+2g
        const float p3 = fmaf(c1[3], c1[3], c1[2] * c1[2]);   // d = 8+2g+1
        // signed-marginal partials: s3 over d&8 -> hi pair; s2: d&4 <=> g&2;
        // s1: d&2 <=> g&1; s0: d&1 -> odd-d pair.
        const float Phi  = p2 + p3;
        const float Podd = p1 + p3;
        const float Pall = Phi + p0 + p1;
        float s3 = Phi, s2 = Pall * f2, s1 = Pall * f1, s0 = Podd;
        // reduce over the 4 g-groups holding this sample (lanes col+16g)
        s3 += __shfl_xor(s3, 16); s2 += __shfl_xor(s2, 16);
        s1 += __shfl_xor(s1, 16); s0 += __shfl_xor(s0, 16);
        s3 += __shfl_xor(s3, 32); s2 += __shfl_xor(s2, 32);
        s1 += __shfl_xor(s1, 32); s0 += __shfl_xor(s0, 32);
        // my own sample (b = base + 16g + col) is the n==g tile
        if (g == n) { e3 = s3; e2 = s2; e1 = s1; e0 = s0; }
    }

    if (b < B) {
        float4 ev;
        ev.x = fmaf(-2.0f, e3, 1.0f);
        ev.y = fmaf(-2.0f, e2, 1.0f);
        ev.z = fmaf(-2.0f, e1, 1.0f);
        ev.w = fmaf(-2.0f, e0, 1.0f);
        reinterpret_cast<float4*>(out)[b] = ev;
    }
}

extern "C" void kernel_launch(void* const* d_in, const int* in_sizes, int n_in,
                              void* d_out, int out_size, void* d_ws, size_t ws_size,
                              hipStream_t stream) {
    const float* x  = (const float*)d_in[0];
    const float* qw = (const float*)d_in[1];
    float* out = (float*)d_out;
    float* ws  = (float*)d_ws;
    const int B = in_sizes[0] / 4;
    const int blocks = (B + 255) / 256;
    qcompose_kernel<<<1, 64, 0, stream>>>(qw, ws);
    qlayer_kernel<<<blocks, 256, 0, stream>>>(x, ws, out, B);
}